// Round 6
// baseline (2820.836 us; speedup 1.0000x reference)
//
#include <hip/hip_runtime.h>
#include <hip/hip_bf16.h>
#include <math.h>

#define NB  1024
#define T   256
#define H   128
#define Z0  64
#define D   8
#define MH  256

typedef __attribute__((ext_vector_type(8))) _Float16 half8;
typedef __attribute__((ext_vector_type(4))) _Float16 half4;
typedef __attribute__((ext_vector_type(4))) float f32x4;
typedef unsigned long long u64;

#define INV2048 4.8828125e-4f

// fragment indices (hi16/lo16 frag = 1024B, lo8 frag = 512B)
#define OFF_F1 0
#define OFF_F2 64
#define OFF_F3 192
#define OFF_G1 256
#define OFF_G2 320
#define OFF_G3 448
#define OFF_R1 512
#define OFF_R2 576
#define OFF_I2 584
#define NFRAG  648

// d_ws layout (bytes) — unchanged footprint
#define WS_HI16 0
#define WS_LO16 663552                     // 648*1024
#define WS_LO8  1327104                    // + 648*1024
#define WS_EX   1658880                    // 64 groups * 36864 (2 roles * 2 parity * 9216)
#define WS_FLG  4018176                    // 64 groups * 256B int flags

// pin a value in VGPRs
#define KEEP(x) asm volatile("" : "+v"(x))

__device__ __forceinline__ f32x4 mfmaH(half8 a, half8 b, f32x4 c){
    return __builtin_amdgcn_mfma_f32_16x16x32_f16(a, b, c, 0, 0, 0);
}
__device__ __forceinline__ float ftanh(float x){
    float e = __expf(2.0f * x);
    return 1.0f - 2.0f * __builtin_amdgcn_rcpf(e + 1.0f);
}
__device__ __forceinline__ unsigned char f16_to_e5m2(_Float16 h){
    unsigned short hu = *reinterpret_cast<unsigned short*>(&h);
    return (unsigned char)((hu + 0x80) >> 8);
}
__device__ __forceinline__ half8 expandQ(u64 qw){
    unsigned int lo = (unsigned int)qw, hi = (unsigned int)(qw >> 32);
    union { unsigned int u[4]; half8 h; } u;
    u.u[0] = ((lo & 0xFFu) << 8) | ((lo & 0xFF00u) << 16);
    u.u[1] = ((lo >> 8) & 0xFF00u) | (lo & 0xFF000000u);
    u.u[2] = ((hi & 0xFFu) << 8) | ((hi & 0xFF00u) << 16);
    u.u[3] = ((hi >> 8) & 0xFF00u) | (hi & 0xFF000000u);
    return u.h;
}

// ---- system-scope fine-grained exchange (write-through to IF$) ----
__device__ __forceinline__ void st_sys4(float* p, f32x4 v){
    union { f32x4 v; u64 q[2]; } c; c.v = v;
    u64* d = reinterpret_cast<u64*>(p);
    __hip_atomic_store(d,     c.q[0], __ATOMIC_RELAXED, __HIP_MEMORY_SCOPE_SYSTEM);
    __hip_atomic_store(d + 1, c.q[1], __ATOMIC_RELAXED, __HIP_MEMORY_SCOPE_SYSTEM);
}
__device__ __forceinline__ f32x4 ld_sys4(float* p){
    union { u64 q[2]; f32x4 v; } c;
    u64* s = reinterpret_cast<u64*>(p);
    c.q[0] = __hip_atomic_load(s,     __ATOMIC_RELAXED, __HIP_MEMORY_SCOPE_SYSTEM);
    c.q[1] = __hip_atomic_load(s + 1, __ATOMIC_RELAXED, __HIP_MEMORY_SCOPE_SYSTEM);
    return c.v;
}
__device__ __forceinline__ void st_sys_i(int* p, int v){
    __hip_atomic_store(p, v, __ATOMIC_RELAXED, __HIP_MEMORY_SCOPE_SYSTEM);
}
__device__ __forceinline__ int ld_sys_i(int* p){
    return __hip_atomic_load(p, __ATOMIC_RELAXED, __HIP_MEMORY_SCOPE_SYSTEM);
}

// ---- swizzled LDS accessors: [b][k] fp16, XOR (b&7)<<4 (16B granules) ----
__device__ __forceinline__ half8 ldB(const _Float16* buf, int sb, int kt, int b, int q){
    const char* p = reinterpret_cast<const char*>(buf);
    return *reinterpret_cast<const half8*>(p + ((b*sb + kt*64 + q*16) ^ ((b & 7) << 4)));
}
__device__ __forceinline__ void stChunk(_Float16* buf, int sb, int b, int k0, half4 v){
    char* p = reinterpret_cast<char*>(buf);
    *reinterpret_cast<half4*>(p + ((b*sb + k0*2) ^ ((b & 7) << 4))) = v;
}
__device__ __forceinline__ void stOne(_Float16* buf, int sb, int b, int k, _Float16 v){
    char* p = reinterpret_cast<char*>(buf);
    *reinterpret_cast<_Float16*>(p + ((b*sb + k*2) ^ ((b & 7) << 4))) = v;
}
__device__ __forceinline__ u64 ldsQ(const char* base, int fragRel, int l){
    return *reinterpret_cast<const u64*>(base + fragRel*512 + l*8);
}

template<bool DOTANH>
__device__ __forceinline__ void storeOut(f32x4 m, f32x4 c, _Float16* Oh, _Float16* Ol, int b, int k0){
    half4 hh, ll;
    #pragma unroll
    for (int r = 0; r < 4; ++r){
        float v = m[r] + c[r]*INV2048;
        if (DOTANH) v = ftanh(v);
        _Float16 h = (_Float16)v;
        hh[r] = h;
        ll[r] = (_Float16)((v - (float)h)*2048.0f);
    }
    stChunk(Oh, 512, b, k0, hh);
    stChunk(Ol, 512, b, k0, ll);
}
__device__ __forceinline__ void storeA1(const float* v4, _Float16* Oh, _Float16* Ol, int b, int k0){
    half4 hh, ll;
    #pragma unroll
    for (int r = 0; r < 4; ++r){
        float v = v4[r];
        _Float16 h = (_Float16)v;
        hh[r] = h;
        ll[r] = (_Float16)((v - (float)h)*2048.0f);
    }
    stChunk(Oh, 256, b, k0, hh);
    stChunk(Ol, 256, b, k0, ll);
}
__device__ __forceinline__ void stOne2(_Float16* Oh, _Float16* Ol, int b, int k, float v){
    _Float16 h = (_Float16)v;
    stOne(Oh, 512, b, k, h);
    stOne(Ol, 512, b, k, (_Float16)((v - (float)h)*2048.0f));
}

// L1 single-column: weights hi+lo in VGPRs, K=128
__device__ __forceinline__ void layerOneReg4(
    const half8* Wh, const half8* Wl,
    const _Float16* Bh, const _Float16* Bl, int sbIn,
    _Float16* Oh, _Float16* Ol, const float* bias, int n, int b, int q)
{
    f32x4 m = *reinterpret_cast<const f32x4*>(bias + n*16 + 4*q);
    f32x4 c = {0.f,0.f,0.f,0.f};
    #pragma unroll
    for (int kt = 0; kt < 4; ++kt){
        half8 bh = ldB(Bh, sbIn, kt, b, q);
        half8 bl = ldB(Bl, sbIn, kt, b, q);
        m = mfmaH(Wh[kt], bh, m);
        c = mfmaH(Wh[kt], bl, c);
        c = mfmaH(Wl[kt], bh, c);
    }
    storeOut<true>(m, c, Oh, Ol, b, n*16 + 4*q);
}
// L2 single-column: hi VGPR, lo e5m2-LDS, K=256
__device__ __forceinline__ void layerOneLds2(
    const half8* Wh, const char* WloLds, int f0, int l,
    const _Float16* Bh, const _Float16* Bl,
    _Float16* Oh, _Float16* Ol, const float* bias, int n, int b, int q)
{
    f32x4 m = *reinterpret_cast<const f32x4*>(bias + n*16 + 4*q);
    f32x4 c = {0.f,0.f,0.f,0.f};
    #pragma unroll
    for (int kt = 0; kt < 8; ++kt){
        half8 bh = ldB(Bh, 512, kt, b, q);
        half8 bl = ldB(Bl, 512, kt, b, q);
        half8 wl = expandQ(ldsQ(WloLds, f0 + kt, l));
        m = mfmaH(Wh[kt], bh, m);
        c = mfmaH(Wh[kt], bl, c);
        c = mfmaH(wl, bh, c);
    }
    storeOut<true>(m, c, Oh, Ol, b, n*16 + 4*q);
}
// L3: hi VGPR + e5m2-LDS lo, result fp32 regs
__device__ __forceinline__ f32x4 layerOneLds8(
    const half8* Wh, const char* WloLds, int f0, int l,
    const _Float16* Bh, const _Float16* Bl,
    const float* bias, int n0, int b, int q)
{
    f32x4 m = *reinterpret_cast<const f32x4*>(bias + n0*16 + 4*q);
    f32x4 c = {0.f,0.f,0.f,0.f};
    #pragma unroll
    for (int kt = 0; kt < 8; ++kt){
        half8 bh = ldB(Bh, 512, kt, b, q);
        half8 bl = ldB(Bl, 512, kt, b, q);
        half8 wl = expandQ(ldsQ(WloLds, f0 + kt, l));
        m = mfmaH(Wh[kt], bh, m);
        c = mfmaH(Wh[kt], bl, c);
        c = mfmaH(wl, bh, c);
    }
    #pragma unroll
    for (int r = 0; r < 4; ++r) m[r] += c[r]*INV2048;
    return m;
}

// ---- pack: hi16 + lo16 (fp16) + lo8 (e5m2 of scaled residual) ----
__global__ __launch_bounds__(64)
void pack_weights(const float* __restrict__ fW1, const float* __restrict__ fW2, const float* __restrict__ fW3,
                  const float* __restrict__ gW1, const float* __restrict__ gW2, const float* __restrict__ gW3,
                  const float* __restrict__ rW1, const float* __restrict__ rW2, const float* __restrict__ iW2,
                  unsigned char* __restrict__ ws)
{
    int f = blockIdx.x, l = threadIdx.x;
    // R2 special pack: per (role,w8) zero-padded A-fragment for the fused readout-L2
    if (f >= OFF_R2 && f < OFF_I2){
        int w8r = f - OFF_R2, d = l & 15, qq = l >> 4;
        half8 v0, v1;
        #pragma unroll
        for (int j = 0; j < 8; ++j){
            int kk = qq*8 + j;
            bool ok = (d < 8) && (kk < 16);
            v0[j] = ok ? (_Float16)rW2[(w8r*16 + kk)*8 + d]        : (_Float16)0.f;
            v1[j] = ok ? (_Float16)rW2[(128 + w8r*16 + kk)*8 + d]  : (_Float16)0.f;
        }
        reinterpret_cast<half8*>(ws + WS_HI16)[(size_t)f*64 + l] = v0;
        reinterpret_cast<half8*>(ws + WS_LO16)[(size_t)f*64 + l] = v1;
        *reinterpret_cast<u64*>(ws + WS_LO8 + (size_t)f*512 + l*8) = 0ull;
        return;
    }
    const float* W; int KT, base, ld, ncols;
    if      (f <  64) { W = fW1+256; KT=4; base=OFF_F1; ld=256; ncols=256; }  // skip t-row 0
    else if (f < 192) { W = fW2;     KT=8; base=OFF_F2; ld=256; ncols=256; }
    else if (f < 256) { W = fW3;     KT=8; base=OFF_F3; ld=128; ncols=128; }
    else if (f < 320) { W = gW1+256; KT=4; base=OFF_G1; ld=256; ncols=256; }
    else if (f < 448) { W = gW2;     KT=8; base=OFF_G2; ld=256; ncols=256; }
    else if (f < 512) { W = gW3;     KT=8; base=OFF_G3; ld=128; ncols=128; }
    else if (f < 576) { W = rW1;     KT=4; base=OFF_R1; ld=256; ncols=256; }
    else              { W = iW2;     KT=8; base=OFF_I2; ld=128; ncols=128; }
    int rel = f - base, n = rel / KT, kt = rel % KT;
    int krow = kt*32 + (l >> 4)*8;
    int col  = n*16  + (l & 15);
    half8 vh, vl; u64 qw = 0;
    #pragma unroll
    for (int j = 0; j < 8; ++j){
        float x = (col < ncols) ? W[(size_t)(krow + j)*ld + col] : 0.0f;
        _Float16 h = (_Float16)x;
        vh[j] = h;
        _Float16 r16 = (_Float16)((x - (float)h) * 2048.0f);
        vl[j] = r16;
        qw |= (u64)f16_to_e5m2(r16) << (8*j);
    }
    reinterpret_cast<half8*>(ws + WS_HI16)[(size_t)f*64 + l] = vh;
    reinterpret_cast<half8*>(ws + WS_LO16)[(size_t)f*64 + l] = vl;
    *reinterpret_cast<u64*>(ws + WS_LO8 + (size_t)f*512 + l*8) = qw;
}

__global__ __launch_bounds__(256)
void zero_flags(unsigned char* ws){
    int* fl = (int*)(ws + WS_FLG);
    #pragma unroll
    for (int i = 0; i < 16; ++i) fl[threadIdx.x + i*256] = 0;
}

// pre-fill out with rb2 broadcast (atomics accumulate the readout partials on top)
__global__ __launch_bounds__(256)
void prefill_out(const float* __restrict__ rb2, float* __restrict__ out){
    f32x4 v0, v1;
    #pragma unroll
    for (int r = 0; r < 4; ++r){ v0[r] = rb2[r]; v1[r] = rb2[4+r]; }
    size_t i = ((size_t)blockIdx.x*256 + threadIdx.x)*2;
    f32x4* o = reinterpret_cast<f32x4*>(out);
    o[i] = v0; o[i+1] = v1;
}

// ---- main: 128 WGs (64 groups x {f,g}), 1024 thr (16 waves, 4/SIMD) ----
// waves 0-7: SDE state, L3, exchange; waves 8-15: L1/L2 helpers + readout.
__global__ __launch_bounds__(1024, 4)
void sde_main(const float* __restrict__ init_noise, const float* __restrict__ ts,
              const float* __restrict__ bm,
              const float* __restrict__ iW1, const float* __restrict__ ib1,
              const float* __restrict__ ib2,
              const float* __restrict__ fb1, const float* __restrict__ fW1r,
              const float* __restrict__ fb2, const float* __restrict__ fb3,
              const float* __restrict__ gb1, const float* __restrict__ gW1r,
              const float* __restrict__ gb2, const float* __restrict__ gb3,
              const float* __restrict__ rb1,
              unsigned char* __restrict__ ws,
              float* __restrict__ out)
{
    const int tid  = threadIdx.x;
    const int w16  = tid >> 6;         // 0..15
    const int l    = tid & 63;
    const int q    = l >> 4;
    const int b    = l & 15;
    const int bid  = blockIdx.x;
    const int role  = (bid >= 64) ? 1 : 0;        // 0=f, 1=g
    const int group = bid & 63;
    const int row0  = group * 16;
    const bool stateW = (w16 < 8);     // wave-uniform role split
    const int wr   = w16 - 8;          // readout-wave index (valid when !stateW)

    __shared__ __align__(16) char Wlo2[65536];            // own L2 lo8 frags
    __shared__ __align__(16) char Wlo3[32768];            // own L3 lo8 frags
    __shared__ __align__(16) _Float16 A1h[16*128], A1l[16*128];
    __shared__ __align__(16) _Float16 H1h[16*256], H1l[16*256];
    __shared__ __align__(16) _Float16 H2h[16*256], H2l[16*256];
    __shared__ __align__(16) _Float16 Y1[16*128];
    __shared__ __align__(16) _Float16 Rb[8*256];          // per-readout-wave bounce
    __shared__ __align__(16) float s_b1[256];
    __shared__ __align__(16) float s_w1r0[256];
    __shared__ __align__(16) float s_bp[256];
    __shared__ __align__(16) float s_b2[256];
    __shared__ __align__(16) float s_b3[128];
    __shared__ __align__(16) float s_rb1h[128];

    const float* b1p = role ? gb1 : fb1;
    const float* w1p = role ? gW1r : fW1r;
    const float* b2p = role ? gb2 : fb2;
    const float* b3p = role ? gb3 : fb3;
    const int o1 = role ? OFF_G1 : OFF_F1;
    const int o2 = role ? OFF_G2 : OFF_F2;
    const int o3 = role ? OFF_G3 : OFF_F3;

    // exchange blob: per group 36864B; per role 18432B; per parity 9216B (v3 only)
    char* exg = (char*)ws + WS_EX + (size_t)group*36864;
    float* Xown = (float*)(exg + role*18432);
    float* Xpar = (float*)(exg + (1-role)*18432);
    int* flags   = (int*)(ws + WS_FLG + (size_t)group*256);
    int* flagOwn = flags + role;
    int* flagPar = flags + (1 - role);

    // ---- staging ----
    if (tid < 256){ s_b1[tid] = b1p[tid]; s_w1r0[tid] = w1p[tid]; s_b2[tid] = b2p[tid]; }
    else if (tid < 384){ s_b3[tid-256] = b3p[tid-256]; }
    else if (tid < 512){ s_rb1h[tid-384] = rb1[role*128 + (tid-384)]; }
    float* zb = reinterpret_cast<float*>(H2h);            // alias (init only): 1024 floats
    zb[tid] = init_noise[row0*Z0 + tid];
    {   // stage own lo8 tables into LDS (1024 threads)
        f32x4* d2 = (f32x4*)Wlo2; const f32x4* s2 = (const f32x4*)(ws + WS_LO8 + (size_t)o2*512);
        #pragma unroll
        for (int i = 0; i < 4; ++i) d2[tid + i*1024] = s2[tid + i*1024];
        f32x4* d3 = (f32x4*)Wlo3; const f32x4* s3 = (const f32x4*)(ws + WS_LO8 + (size_t)o3*512);
        #pragma unroll
        for (int i = 0; i < 2; ++i) d3[tid + i*1024] = s3[tid + i*1024];
    }
    // ---- resident weights -> VGPRs (per-wave single column n = w16) ----
    const half8* hi  = reinterpret_cast<const half8*>(ws + WS_HI16);
    const half8* lo16 = reinterpret_cast<const half8*>(ws + WS_LO16);
    half8 W1h[4], W1l[4], W2h[8], WX[8];
    #pragma unroll
    for (int kt = 0; kt < 4; ++kt){
        W1h[kt] = hi  [(size_t)(o1 + w16*4 + kt)*64 + l];
        W1l[kt] = lo16[(size_t)(o1 + w16*4 + kt)*64 + l];
    }
    #pragma unroll
    for (int kt = 0; kt < 8; ++kt){
        W2h[kt] = hi[(size_t)(o2 + w16*8 + kt)*64 + l];
    }
    if (stateW){
        #pragma unroll
        for (int kt = 0; kt < 8; ++kt) WX[kt] = hi[(size_t)(o3 + w16*8 + kt)*64 + l];
    } else {
        #pragma unroll
        for (int kt = 0; kt < 4; ++kt) WX[kt] = hi[(size_t)(OFF_R1 + (role*8 + wr)*4 + kt)*64 + l];
        WX[4] = role ? lo16[(size_t)(OFF_R2 + wr)*64 + l] : hi[(size_t)(OFF_R2 + wr)*64 + l];
        WX[5] = WX[4]; WX[6] = WX[4]; WX[7] = WX[4];
    }
    #pragma unroll
    for (int kt = 0; kt < 4; ++kt){ KEEP(W1h[kt]); KEEP(W1l[kt]); }
    #pragma unroll
    for (int kt = 0; kt < 8; ++kt){ KEEP(W2h[kt]); KEEP(WX[kt]); }
    __syncthreads();

    // ---- init MLP layer 1 (fp32 VALU): h = tanh(z@iW1+ib1) -> H1 ----
    {
        const int c = tid & 255, hf = tid >> 8;           // hf 0..3, 4 rows each
        float ac[4]; float bv = ib1[c];
        #pragma unroll
        for (int rr = 0; rr < 4; ++rr) ac[rr] = bv;
        for (int k = 0; k < Z0; ++k){
            float wt = iW1[k*256 + c];
            #pragma unroll
            for (int rr = 0; rr < 4; ++rr) ac[rr] += zb[(hf*4+rr)*Z0 + k] * wt;
        }
        #pragma unroll
        for (int rr = 0; rr < 4; ++rr) stOne2(H1h, H1l, hf*4+rr, c, ftanh(ac[rr]));
    }
    __syncthreads();

    // ---- init MLP layer 2 (MFMA): x0 -> state + A1 + Y1 (waves 0-7) ----
    float y[4], yh[4], fp[4], gp[4], bmv[4];
    if (stateW){
        half8 ih[8], il[8];
        #pragma unroll
        for (int kt = 0; kt < 8; ++kt){
            ih[kt] = hi  [(size_t)(OFF_I2 + w16*8 + kt)*64 + l];
            il[kt] = lo16[(size_t)(OFF_I2 + w16*8 + kt)*64 + l];
        }
        f32x4 m = *reinterpret_cast<const f32x4*>(ib2 + w16*16 + 4*q);
        f32x4 c = {0.f,0.f,0.f,0.f};
        #pragma unroll
        for (int kt = 0; kt < 8; ++kt){
            half8 bh = ldB(H1h, 512, kt, b, q);
            half8 bl = ldB(H1l, 512, kt, b, q);
            m = mfmaH(ih[kt], bh, m);
            c = mfmaH(ih[kt], bl, c);
            c = mfmaH(il[kt], bh, c);
        }
        float xv[4]; half4 hv;
        #pragma unroll
        for (int r = 0; r < 4; ++r){
            float v = m[r] + c[r]*INV2048;
            y[r] = v; yh[r] = v; xv[r] = v; bmv[r] = 0.f;
            hv[r] = (_Float16)v;
        }
        storeA1(xv, A1h, A1l, b, w16*16 + 4*q);
        stChunk(Y1, 256, b, w16*16 + 4*q, hv);
    }

    const float ts0  = ts[0];
    const float dtv  = ts[1] - ts0;
    const float sqdt = sqrtf(dtv);

    #pragma unroll 1
    for (int t = 0; t < T; ++t){
        const float tval = ts0 + (float)t * dtv;
        const int par = t & 1;
        float dWv[4] = {0.f,0.f,0.f,0.f};
        // P0: predictor -> A1 (state waves); s_bp by waves 8-11
        if (stateW && t > 0){
            float nv[4];
            #pragma unroll
            for (int r = 0; r < 4; ++r){
                dWv[r] = bmv[r] * sqdt;
                float nyh = 2.0f*y[r] - yh[r] + fp[r]*dtv + gp[r]*dWv[r];
                yh[r] = nyh; nv[r] = nyh;
            }
            storeA1(nv, A1h, A1l, b, w16*16 + 4*q);
        }
        if (tid >= 512 && tid < 768){
            int c = tid - 512;
            s_bp[c] = s_b1[c] + tval * s_w1r0[c];
        }
        __syncthreads();                                                  // B0
        // bm prefetch for next step (state waves)
        if (stateW && t < T-1){
            f32x4 bv = *reinterpret_cast<const f32x4*>(
                bm + (size_t)t*(NB*H) + (size_t)(row0+b)*H + w16*16 + 4*q);
            #pragma unroll
            for (int r = 0; r < 4; ++r) bmv[r] = bv[r];
        }
        // P1: L1 (K=128), 16 waves x 1 column tile
        layerOneReg4(W1h, W1l, A1h, A1l, 256, H1h, H1l, s_bp, w16, b, q);
        __syncthreads();                                                  // B1
        // P2: L2 (K=256), 16 waves x 1 column tile
        layerOneLds2(W2h, Wlo2, w16*8, l, H1h, H1l, H2h, H2l, s_b2, w16, b, q);
        __syncthreads();                                                  // B2
        // P3 (waves 0-7): L3 -> v3, publish || P5' (waves 8-15): lagged readout
        f32x4 v3 = {0.f,0.f,0.f,0.f};
        f32x4 pr = {0.f,0.f,0.f,0.f};
        if (stateW){
            v3 = layerOneLds8(WX, Wlo3, w16*8, l, H2h, H2l, s_b3, w16, b, q);
            st_sys4(Xown + par*2304 + (b*128 + w16*16 + 4*q), v3);
        } else if (t > 0){
            f32x4 m = *reinterpret_cast<const f32x4*>(s_rb1h + wr*16 + 4*q);
            #pragma unroll
            for (int kt = 0; kt < 4; ++kt) m = mfmaH(WX[kt], ldB(Y1, 256, kt, b, q), m);
            half4 hv;
            #pragma unroll
            for (int r = 0; r < 4; ++r) hv[r] = (_Float16)ftanh(m[r]);
            *reinterpret_cast<half4*>(&Rb[wr*256 + b*16 + 4*q]) = hv;     // same-wave LDS
            half8 bf = *reinterpret_cast<const half8*>(&Rb[wr*256 + b*16 + (q&1)*8]);
            pr = mfmaH(WX[4], bf, pr);   // zero-padded A kills q>=2 garbage
        }
        __syncthreads();                                                  // Bv (drains v3 acks)
        if (tid == 0) st_sys_i(flagOwn, t + 1);
        // readout atomics (waves 8-15) issued during the poll window
        if (!stateW && t > 0 && q < 2){
            float* op = out + (size_t)(row0+b)*(T*D) + (size_t)(t-1)*D + 4*q;
            #pragma unroll
            for (int r = 0; r < 4; ++r) atomicAdd(op + r, pr[r]);
        }
        if (tid == 0){
            while (ld_sys_i(flagPar) < t + 1) __builtin_amdgcn_s_sleep(1);
        }
        __syncthreads();                                                  // B7
        // state waves: read partner v3, corrector, Y1
        if (stateW){
            f32x4 vp = ld_sys4(Xpar + par*2304 + (b*128 + w16*16 + 4*q));
            half4 hv;
            #pragma unroll
            for (int r = 0; r < 4; ++r){
                float fn = role ? vp[r] : v3[r];
                float gn = role ? v3[r] : vp[r];
                if (t > 0) y[r] += 0.5f*dtv*(fp[r] + fn) + 0.5f*(gp[r] + gn)*dWv[r];
                fp[r] = fn; gp[r] = gn;
                hv[r] = (_Float16)y[r];
            }
            stChunk(Y1, 256, b, w16*16 + 4*q, hv);
        }
    }

    // ---- flush: readout for tr = T-1 (waves 8-15) ----
    __syncthreads();
    if (!stateW){
        f32x4 m = *reinterpret_cast<const f32x4*>(s_rb1h + wr*16 + 4*q);
        #pragma unroll
        for (int kt = 0; kt < 4; ++kt) m = mfmaH(WX[kt], ldB(Y1, 256, kt, b, q), m);
        half4 hv;
        #pragma unroll
        for (int r = 0; r < 4; ++r) hv[r] = (_Float16)ftanh(m[r]);
        *reinterpret_cast<half4*>(&Rb[wr*256 + b*16 + 4*q]) = hv;
        half8 bf = *reinterpret_cast<const half8*>(&Rb[wr*256 + b*16 + (q&1)*8]);
        f32x4 pr = {0.f,0.f,0.f,0.f};
        pr = mfmaH(WX[4], bf, pr);
        if (q < 2){
            float* op = out + (size_t)(row0+b)*(T*D) + (size_t)(T-1)*D + 4*q;
            #pragma unroll
            for (int r = 0; r < 4; ++r) atomicAdd(op + r, pr[r]);
        }
    }
}

extern "C" void kernel_launch(void* const* d_in, const int* in_sizes, int n_in,
                              void* d_out, int out_size, void* d_ws, size_t ws_size,
                              hipStream_t stream)
{
    const float* init_noise = (const float*)d_in[0];
    const float* ts  = (const float*)d_in[1];
    const float* bm  = (const float*)d_in[2];
    const float* iW1 = (const float*)d_in[3];
    const float* ib1 = (const float*)d_in[4];
    const float* iW2 = (const float*)d_in[5];
    const float* ib2 = (const float*)d_in[6];
    const float* fW1 = (const float*)d_in[7];
    const float* fb1 = (const float*)d_in[8];
    const float* fW2 = (const float*)d_in[9];
    const float* fb2 = (const float*)d_in[10];
    const float* fW3 = (const float*)d_in[11];
    const float* fb3 = (const float*)d_in[12];
    const float* gW1 = (const float*)d_in[13];
    const float* gb1 = (const float*)d_in[14];
    const float* gW2 = (const float*)d_in[15];
    const float* gb2 = (const float*)d_in[16];
    const float* gW3 = (const float*)d_in[17];
    const float* gb3 = (const float*)d_in[18];
    const float* rW1 = (const float*)d_in[19];
    const float* rb1 = (const float*)d_in[20];
    const float* rW2 = (const float*)d_in[21];
    const float* rb2 = (const float*)d_in[22];

    unsigned char* ws = (unsigned char*)d_ws;

    zero_flags<<<dim3(1), dim3(256), 0, stream>>>(ws);
    pack_weights<<<dim3(NFRAG), dim3(64), 0, stream>>>(
        fW1, fW2, fW3, gW1, gW2, gW3, rW1, rW2, iW2, ws);
    prefill_out<<<dim3(1024), dim3(256), 0, stream>>>(rb2, (float*)d_out);
    sde_main<<<dim3(128), dim3(1024), 0, stream>>>(
        init_noise, ts, bm, iW1, ib1, ib2,
        fb1, fW1, fb2, fb3,
        gb1, gW1, gb2, gb3,
        rb1, ws, (float*)d_out);
}

// Round 7
// 2333.472 us; speedup vs baseline: 1.2089x; 1.2089x over previous
//
#include <hip/hip_runtime.h>
#include <hip/hip_bf16.h>
#include <math.h>

#define NB  1024
#define T   256
#define H   128
#define Z0  64
#define D   8
#define MH  256

typedef __attribute__((ext_vector_type(8))) _Float16 half8;
typedef __attribute__((ext_vector_type(4))) _Float16 half4;
typedef __attribute__((ext_vector_type(4))) float f32x4;
typedef unsigned long long u64;

#define INV2048 4.8828125e-4f

// fragment indices (hi16/lo16 frag = 1024B, lo8 frag = 512B)
#define OFF_F1 0
#define OFF_F2 64
#define OFF_F3 192
#define OFF_G1 256
#define OFF_G2 320
#define OFF_G3 448
#define OFF_R1 512
#define OFF_R2 576
#define OFF_I2 584
#define NFRAG  648

// d_ws layout (bytes) — unchanged footprint
#define WS_HI16 0
#define WS_LO16 663552                     // 648*1024
#define WS_LO8  1327104                    // + 648*1024
#define WS_EX   1658880                    // 64 groups * 36864 (2 roles * 2 parity * 9216)
#define WS_FLG  4018176                    // 64 groups * 256B int flags

// pin a value in VGPRs: compiler can no longer rematerialize it from memory
#define KEEP(x) asm volatile("" : "+v"(x))

__device__ __forceinline__ f32x4 mfmaH(half8 a, half8 b, f32x4 c){
    return __builtin_amdgcn_mfma_f32_16x16x32_f16(a, b, c, 0, 0, 0);
}
__device__ __forceinline__ float ftanh(float x){
    float e = __expf(2.0f * x);
    return 1.0f - 2.0f * __builtin_amdgcn_rcpf(e + 1.0f);
}
// e5m2 byte = round-half-up of fp16's upper byte
__device__ __forceinline__ unsigned char f16_to_e5m2(_Float16 h){
    unsigned short hu = *reinterpret_cast<unsigned short*>(&h);
    return (unsigned char)((hu + 0x80) >> 8);
}
// exact e5m2 -> fp16 expansion of 8 packed bytes (b<<8 per element)
__device__ __forceinline__ half8 expandQ(u64 qw){
    unsigned int lo = (unsigned int)qw, hi = (unsigned int)(qw >> 32);
    union { unsigned int u[4]; half8 h; } u;
    u.u[0] = ((lo & 0xFFu) << 8) | ((lo & 0xFF00u) << 16);
    u.u[1] = ((lo >> 8) & 0xFF00u) | (lo & 0xFF000000u);
    u.u[2] = ((hi & 0xFFu) << 8) | ((hi & 0xFF00u) << 16);
    u.u[3] = ((hi >> 8) & 0xFF00u) | (hi & 0xFF000000u);
    return u.h;
}

// ---- system-scope fine-grained exchange (write-through to IF$, no L2 wb/inv) ----
__device__ __forceinline__ void st_sys4(float* p, f32x4 v){
    union { f32x4 v; u64 q[2]; } c; c.v = v;
    u64* d = reinterpret_cast<u64*>(p);
    __hip_atomic_store(d,     c.q[0], __ATOMIC_RELAXED, __HIP_MEMORY_SCOPE_SYSTEM);
    __hip_atomic_store(d + 1, c.q[1], __ATOMIC_RELAXED, __HIP_MEMORY_SCOPE_SYSTEM);
}
__device__ __forceinline__ f32x4 ld_sys4(float* p){
    union { u64 q[2]; f32x4 v; } c;
    u64* s = reinterpret_cast<u64*>(p);
    c.q[0] = __hip_atomic_load(s,     __ATOMIC_RELAXED, __HIP_MEMORY_SCOPE_SYSTEM);
    c.q[1] = __hip_atomic_load(s + 1, __ATOMIC_RELAXED, __HIP_MEMORY_SCOPE_SYSTEM);
    return c.v;
}
__device__ __forceinline__ void flag_release_sys(int* p, int v){
    __hip_atomic_store(p, v, __ATOMIC_RELAXED, __HIP_MEMORY_SCOPE_SYSTEM);
}
__device__ __forceinline__ void flag_poll_sys(int* p, int v){
    while (__hip_atomic_load(p, __ATOMIC_RELAXED, __HIP_MEMORY_SCOPE_SYSTEM) < v)
        __builtin_amdgcn_s_sleep(1);
}

// ---- swizzled LDS accessors: [b][k] fp16 rows ----
// swizzle v2: sb=512 rows -> XOR (b&15)<<4 ^ (b&1)<<8  => 2-way (free) on
// ds_read_b128 (was (b&7)<<4 => ~8-way, 2.9x). sb=256 rows -> (b&15)<<4 => 2-way.
// Bijective within a row (XOR bits < log2(sb)); write & read use the same XOR.
__device__ __forceinline__ int swz(int sb, int b){
    return ((b & 15) << 4) ^ ((sb == 512) ? ((b & 1) << 8) : 0);
}
__device__ __forceinline__ half8 ldB(const _Float16* buf, int sb, int kt, int b, int q){
    const char* p = reinterpret_cast<const char*>(buf);
    return *reinterpret_cast<const half8*>(p + ((b*sb + kt*64 + q*16) ^ swz(sb, b)));
}
__device__ __forceinline__ void stChunk(_Float16* buf, int sb, int b, int k0, half4 v){
    char* p = reinterpret_cast<char*>(buf);
    *reinterpret_cast<half4*>(p + ((b*sb + k0*2) ^ swz(sb, b))) = v;
}
__device__ __forceinline__ void stOne(_Float16* buf, int sb, int b, int k, _Float16 v){
    char* p = reinterpret_cast<char*>(buf);
    *reinterpret_cast<_Float16*>(p + ((b*sb + k*2) ^ swz(sb, b))) = v;
}
__device__ __forceinline__ u64 ldsQ(const char* base, int fragRel, int l){
    return *reinterpret_cast<const u64*>(base + fragRel*512 + l*8);
}

template<bool DOTANH>
__device__ __forceinline__ void storeOut(f32x4 m, f32x4 c, _Float16* Oh, _Float16* Ol, int b, int k0){
    half4 hh, ll;
    #pragma unroll
    for (int r = 0; r < 4; ++r){
        float v = m[r] + c[r]*INV2048;
        if (DOTANH) v = ftanh(v);
        _Float16 h = (_Float16)v;
        hh[r] = h;
        ll[r] = (_Float16)((v - (float)h)*2048.0f);
    }
    stChunk(Oh, 512, b, k0, hh);
    stChunk(Ol, 512, b, k0, ll);
}
__device__ __forceinline__ void storeA1(const float* v4, _Float16* Oh, _Float16* Ol, int b, int k0){
    half4 hh, ll;
    #pragma unroll
    for (int r = 0; r < 4; ++r){
        float v = v4[r];
        _Float16 h = (_Float16)v;
        hh[r] = h;
        ll[r] = (_Float16)((v - (float)h)*2048.0f);
    }
    stChunk(Oh, 256, b, k0, hh);
    stChunk(Ol, 256, b, k0, ll);
}
__device__ __forceinline__ void stOne2(_Float16* Oh, _Float16* Ol, int b, int k, float v){
    _Float16 h = (_Float16)v;
    stOne(Oh, 512, b, k, h);
    stOne(Ol, 512, b, k, (_Float16)((v - (float)h)*2048.0f));
}

// L1: weights hi+lo fully in VGPRs. Chain-split: c accumulators use two
// independent half-chains (4-dep each instead of 8-dep) summed at the end.
template<int KT, bool DOTANH>
__device__ __forceinline__ void layerPairReg(
    const half8* Wh0, const half8* Wh1, const half8* Wl0, const half8* Wl1,
    const _Float16* Bh, const _Float16* Bl, int sbIn,
    _Float16* Oh, _Float16* Ol, const float* bias, int n0, int n1, int b, int q)
{
    f32x4 m0 = *reinterpret_cast<const f32x4*>(bias + n0*16 + 4*q);
    f32x4 m1 = *reinterpret_cast<const f32x4*>(bias + n1*16 + 4*q);
    f32x4 c0a = {0.f,0.f,0.f,0.f}, c0b = {0.f,0.f,0.f,0.f};
    f32x4 c1a = {0.f,0.f,0.f,0.f}, c1b = {0.f,0.f,0.f,0.f};
    #pragma unroll
    for (int kt = 0; kt < KT; ++kt){
        half8 bh = ldB(Bh, sbIn, kt, b, q);
        half8 bl = ldB(Bl, sbIn, kt, b, q);
        m0  = mfmaH(Wh0[kt], bh, m0);
        m1  = mfmaH(Wh1[kt], bh, m1);
        c0a = mfmaH(Wh0[kt], bl, c0a);
        c1a = mfmaH(Wh1[kt], bl, c1a);
        c0b = mfmaH(Wl0[kt], bh, c0b);
        c1b = mfmaH(Wl1[kt], bh, c1b);
    }
    f32x4 c0, c1;
    #pragma unroll
    for (int r = 0; r < 4; ++r){ c0[r] = c0a[r] + c0b[r]; c1[r] = c1a[r] + c1b[r]; }
    storeOut<DOTANH>(m0, c0, Oh, Ol, b, n0*16 + 4*q);
    storeOut<DOTANH>(m1, c1, Oh, Ol, b, n1*16 + 4*q);
}
// L2: hi in VGPRs, lo as e5m2 bytes in LDS expanded to fp16 (chain-split c)
template<int KT, bool DOTANH>
__device__ __forceinline__ void layerPairLds(
    const half8* Wh0, const half8* Wh1, const char* WloLds, int f0, int f1, int l,
    const _Float16* Bh, const _Float16* Bl, int sbIn,
    _Float16* Oh, _Float16* Ol, const float* bias, int n0, int n1, int b, int q)
{
    f32x4 m0 = *reinterpret_cast<const f32x4*>(bias + n0*16 + 4*q);
    f32x4 m1 = *reinterpret_cast<const f32x4*>(bias + n1*16 + 4*q);
    f32x4 c0a = {0.f,0.f,0.f,0.f}, c0b = {0.f,0.f,0.f,0.f};
    f32x4 c1a = {0.f,0.f,0.f,0.f}, c1b = {0.f,0.f,0.f,0.f};
    #pragma unroll
    for (int kt = 0; kt < KT; ++kt){
        half8 bh = ldB(Bh, sbIn, kt, b, q);
        half8 bl = ldB(Bl, sbIn, kt, b, q);
        half8 w0l = expandQ(ldsQ(WloLds, f0 + kt, l));
        half8 w1l = expandQ(ldsQ(WloLds, f1 + kt, l));
        m0  = mfmaH(Wh0[kt], bh, m0);
        m1  = mfmaH(Wh1[kt], bh, m1);
        c0a = mfmaH(Wh0[kt], bl, c0a);
        c1a = mfmaH(Wh1[kt], bl, c1a);
        c0b = mfmaH(w0l, bh, c0b);
        c1b = mfmaH(w1l, bh, c1b);
    }
    f32x4 c0, c1;
    #pragma unroll
    for (int r = 0; r < 4; ++r){ c0[r] = c0a[r] + c0b[r]; c1[r] = c1a[r] + c1b[r]; }
    storeOut<DOTANH>(m0, c0, Oh, Ol, b, n0*16 + 4*q);
    storeOut<DOTANH>(m1, c1, Oh, Ol, b, n1*16 + 4*q);
}
// L3: hi VGPR + e5m2-LDS lo, result fp32 regs (chain-split c)
__device__ __forceinline__ f32x4 layerOneLds8(
    const half8* Wh, const char* WloLds, int f0, int l,
    const _Float16* Bh, const _Float16* Bl,
    const float* bias, int n0, int b, int q)
{
    f32x4 m = *reinterpret_cast<const f32x4*>(bias + n0*16 + 4*q);
    f32x4 ca = {0.f,0.f,0.f,0.f}, cb = {0.f,0.f,0.f,0.f};
    #pragma unroll
    for (int kt = 0; kt < 8; ++kt){
        half8 bh = ldB(Bh, 512, kt, b, q);
        half8 bl = ldB(Bl, 512, kt, b, q);
        half8 wl = expandQ(ldsQ(WloLds, f0 + kt, l));
        m  = mfmaH(Wh[kt], bh, m);
        ca = mfmaH(Wh[kt], bl, ca);
        cb = mfmaH(wl, bh, cb);
    }
    #pragma unroll
    for (int r = 0; r < 4; ++r) m[r] += (ca[r] + cb[r])*INV2048;
    return m;
}

// ---- pack: hi16 + lo16 (fp16) + lo8 (e5m2 of scaled residual) ----
__global__ __launch_bounds__(64)
void pack_weights(const float* __restrict__ fW1, const float* __restrict__ fW2, const float* __restrict__ fW3,
                  const float* __restrict__ gW1, const float* __restrict__ gW2, const float* __restrict__ gW3,
                  const float* __restrict__ rW1, const float* __restrict__ rW2, const float* __restrict__ iW2,
                  unsigned char* __restrict__ ws)
{
    int f = blockIdx.x, l = threadIdx.x;
    // R2 special pack: per (role,w8) zero-padded A-fragment for the fused readout-L2
    if (f >= OFF_R2 && f < OFF_I2){
        int w8r = f - OFF_R2, d = l & 15, qq = l >> 4;
        half8 v0, v1;
        #pragma unroll
        for (int j = 0; j < 8; ++j){
            int kk = qq*8 + j;
            bool ok = (d < 8) && (kk < 16);
            v0[j] = ok ? (_Float16)rW2[(w8r*16 + kk)*8 + d]        : (_Float16)0.f;
            v1[j] = ok ? (_Float16)rW2[(128 + w8r*16 + kk)*8 + d]  : (_Float16)0.f;
        }
        reinterpret_cast<half8*>(ws + WS_HI16)[(size_t)f*64 + l] = v0;
        reinterpret_cast<half8*>(ws + WS_LO16)[(size_t)f*64 + l] = v1;
        *reinterpret_cast<u64*>(ws + WS_LO8 + (size_t)f*512 + l*8) = 0ull;
        return;
    }
    const float* W; int KT, base, ld, ncols;
    if      (f <  64) { W = fW1+256; KT=4; base=OFF_F1; ld=256; ncols=256; }  // skip t-row 0
    else if (f < 192) { W = fW2;     KT=8; base=OFF_F2; ld=256; ncols=256; }
    else if (f < 256) { W = fW3;     KT=8; base=OFF_F3; ld=128; ncols=128; }
    else if (f < 320) { W = gW1+256; KT=4; base=OFF_G1; ld=256; ncols=256; }
    else if (f < 448) { W = gW2;     KT=8; base=OFF_G2; ld=256; ncols=256; }
    else if (f < 512) { W = gW3;     KT=8; base=OFF_G3; ld=128; ncols=128; }
    else if (f < 576) { W = rW1;     KT=4; base=OFF_R1; ld=256; ncols=256; }
    else              { W = iW2;     KT=8; base=OFF_I2; ld=128; ncols=128; }
    int rel = f - base, n = rel / KT, kt = rel % KT;
    int krow = kt*32 + (l >> 4)*8;
    int col  = n*16  + (l & 15);
    half8 vh, vl; u64 qw = 0;
    #pragma unroll
    for (int j = 0; j < 8; ++j){
        float x = (col < ncols) ? W[(size_t)(krow + j)*ld + col] : 0.0f;
        _Float16 h = (_Float16)x;
        vh[j] = h;
        _Float16 r16 = (_Float16)((x - (float)h) * 2048.0f);
        vl[j] = r16;
        qw |= (u64)f16_to_e5m2(r16) << (8*j);
    }
    reinterpret_cast<half8*>(ws + WS_HI16)[(size_t)f*64 + l] = vh;
    reinterpret_cast<half8*>(ws + WS_LO16)[(size_t)f*64 + l] = vl;
    *reinterpret_cast<u64*>(ws + WS_LO8 + (size_t)f*512 + l*8) = qw;
}

__global__ __launch_bounds__(256)
void zero_flags(unsigned char* ws){
    int* fl = (int*)(ws + WS_FLG);
    #pragma unroll
    for (int i = 0; i < 16; ++i) fl[threadIdx.x + i*256] = 0;
}

// pre-fill out with rb2 broadcast (atomics accumulate the readout partials on top)
__global__ __launch_bounds__(256)
void prefill_out(const float* __restrict__ rb2, float* __restrict__ out){
    f32x4 v0, v1;
    #pragma unroll
    for (int r = 0; r < 4; ++r){ v0[r] = rb2[r]; v1[r] = rb2[4+r]; }
    size_t i = ((size_t)blockIdx.x*256 + threadIdx.x)*2;
    f32x4* o = reinterpret_cast<f32x4*>(out);
    o[i] = v0; o[i+1] = v1;
}

// ---- main: 128 WGs (64 groups x {f,g}), 512 thr, weights resident ----
__global__ __launch_bounds__(512, 2)
void sde_main(const float* __restrict__ init_noise, const float* __restrict__ ts,
              const float* __restrict__ bm,
              const float* __restrict__ iW1, const float* __restrict__ ib1,
              const float* __restrict__ ib2,
              const float* __restrict__ fb1, const float* __restrict__ fW1r,
              const float* __restrict__ fb2, const float* __restrict__ fb3,
              const float* __restrict__ gb1, const float* __restrict__ gW1r,
              const float* __restrict__ gb2, const float* __restrict__ gb3,
              const float* __restrict__ rb1,
              unsigned char* __restrict__ ws,
              float* __restrict__ out)
{
    const int tid  = threadIdx.x;
    const int wv   = tid >> 6;         // 0..7
    const int l    = tid & 63;
    const int q    = l >> 4;
    const int b    = l & 15;
    const int bid  = blockIdx.x;
    const int role  = (bid >= 64) ? 1 : 0;        // 0=f, 1=g
    const int group = bid & 63;
    const int row0  = group * 16;
    const int w8    = wv;

    __shared__ __align__(16) char Wlo2[65536];            // own L2 lo8 frags
    __shared__ __align__(16) char Wlo3[32768];            // own L3 lo8 frags
    __shared__ __align__(16) _Float16 A1h[16*128], A1l[16*128];
    __shared__ __align__(16) _Float16 H1h[16*256], H1l[16*256];
    __shared__ __align__(16) _Float16 H2h[16*256], H2l[16*256];
    __shared__ __align__(16) _Float16 Y1[16*128];
    __shared__ __align__(16) _Float16 Rb[8*256];          // per-wave 16x16 readout bounce
    __shared__ __align__(16) float s_b1[256];
    __shared__ __align__(16) float s_w1r0[256];
    __shared__ __align__(16) float s_bp[256];
    __shared__ __align__(16) float s_b2[256];
    __shared__ __align__(16) float s_b3[128];
    __shared__ __align__(16) float s_rb1h[128];

    const float* b1p = role ? gb1 : fb1;
    const float* w1p = role ? gW1r : fW1r;
    const float* b2p = role ? gb2 : fb2;
    const float* b3p = role ? gb3 : fb3;
    const int o1 = role ? OFF_G1 : OFF_F1;
    const int o2 = role ? OFF_G2 : OFF_F2;
    const int o3 = role ? OFF_G3 : OFF_F3;

    // exchange blob: per group 36864B; per role 18432B; per parity 9216B (v3 only)
    char* exg = (char*)ws + WS_EX + (size_t)group*36864;
    float* Xown = (float*)(exg + role*18432);
    float* Xpar = (float*)(exg + (1-role)*18432);
    int* flags   = (int*)(ws + WS_FLG + (size_t)group*256);
    int* flagOwn = flags + role;
    int* flagPar = flags + (1 - role);

    // ---- staging ----
    if (tid < 256){ s_b1[tid] = b1p[tid]; s_w1r0[tid] = w1p[tid]; s_b2[tid] = b2p[tid]; }
    else if (tid < 384){ s_b3[tid-256] = b3p[tid-256]; }
    else { s_rb1h[tid-384] = rb1[role*128 + (tid-384)]; }
    float* zb = reinterpret_cast<float*>(H2h);            // alias (init only)
    zb[tid]       = init_noise[row0*Z0 + tid];
    zb[tid + 512] = init_noise[row0*Z0 + 512 + tid];
    {   // stage own lo8 tables into LDS
        f32x4* d2 = (f32x4*)Wlo2; const f32x4* s2 = (const f32x4*)(ws + WS_LO8 + (size_t)o2*512);
        #pragma unroll
        for (int i = 0; i < 8; ++i) d2[tid + i*512] = s2[tid + i*512];
        f32x4* d3 = (f32x4*)Wlo3; const f32x4* s3 = (const f32x4*)(ws + WS_LO8 + (size_t)o3*512);
        #pragma unroll
        for (int i = 0; i < 4; ++i) d3[tid + i*512] = s3[tid + i*512];
    }
    // ---- resident weights -> VGPRs ----
    const half8* hi  = reinterpret_cast<const half8*>(ws + WS_HI16);
    const half8* lo16 = reinterpret_cast<const half8*>(ws + WS_LO16);
    half8 W1h[2][4], W1l[2][4], W2h[2][8], W3h[8], WR1[4], WR2;
    #pragma unroll
    for (int kt = 0; kt < 4; ++kt){
        W1h[0][kt] = hi  [(size_t)(o1 + (2*w8  )*4 + kt)*64 + l];
        W1h[1][kt] = hi  [(size_t)(o1 + (2*w8+1)*4 + kt)*64 + l];
        W1l[0][kt] = lo16[(size_t)(o1 + (2*w8  )*4 + kt)*64 + l];
        W1l[1][kt] = lo16[(size_t)(o1 + (2*w8+1)*4 + kt)*64 + l];
        WR1[kt]    = hi  [(size_t)(OFF_R1 + (role*8 + w8)*4 + kt)*64 + l];
    }
    #pragma unroll
    for (int kt = 0; kt < 8; ++kt){
        W2h[0][kt] = hi[(size_t)(o2 + (2*w8  )*8 + kt)*64 + l];
        W2h[1][kt] = hi[(size_t)(o2 + (2*w8+1)*8 + kt)*64 + l];
        W3h[kt]    = hi[(size_t)(o3 + w8*8 + kt)*64 + l];
    }
    // fused-readout A-frag: role0 from hi slot, role1 from lo16 slot (see pack)
    WR2 = role ? lo16[(size_t)(OFF_R2 + w8)*64 + l] : hi[(size_t)(OFF_R2 + w8)*64 + l];

    // pin the per-step weights in VGPRs (defeats rematerialization from memory)
    #pragma unroll
    for (int s = 0; s < 2; ++s){
        #pragma unroll
        for (int kt = 0; kt < 4; ++kt){ KEEP(W1h[s][kt]); KEEP(W1l[s][kt]); }
        #pragma unroll
        for (int kt = 0; kt < 8; ++kt){ KEEP(W2h[s][kt]); }
    }
    #pragma unroll
    for (int kt = 0; kt < 8; ++kt){ KEEP(W3h[kt]); }
    __syncthreads();

    // ---- init MLP layer 1 (fp32 VALU): h = tanh(z@iW1+ib1) -> H1 ----
    {
        const int c = tid & 255, hf = tid >> 8;
        float ac[8]; float bv = ib1[c];
        #pragma unroll
        for (int rr = 0; rr < 8; ++rr) ac[rr] = bv;
        for (int k = 0; k < Z0; ++k){
            float wt = iW1[k*256 + c];
            #pragma unroll
            for (int rr = 0; rr < 8; ++rr) ac[rr] += zb[(hf*8+rr)*Z0 + k] * wt;
        }
        #pragma unroll
        for (int rr = 0; rr < 8; ++rr) stOne2(H1h, H1l, hf*8+rr, c, ftanh(ac[rr]));
    }
    __syncthreads();

    // ---- init MLP layer 2 (MFMA, hi/lo fp16 transient): x0 -> state + A1 + Y1 ----
    float y[4], yh[4], fp[4], gp[4], bmv[4];
    {
        half8 ih[8], il[8];
        #pragma unroll
        for (int kt = 0; kt < 8; ++kt){
            ih[kt] = hi  [(size_t)(OFF_I2 + w8*8 + kt)*64 + l];
            il[kt] = lo16[(size_t)(OFF_I2 + w8*8 + kt)*64 + l];
        }
        f32x4 m = *reinterpret_cast<const f32x4*>(ib2 + w8*16 + 4*q);
        f32x4 ca = {0.f,0.f,0.f,0.f}, cb = {0.f,0.f,0.f,0.f};
        #pragma unroll
        for (int kt = 0; kt < 8; ++kt){
            half8 bh = ldB(H1h, 512, kt, b, q);
            half8 bl = ldB(H1l, 512, kt, b, q);
            m  = mfmaH(ih[kt], bh, m);
            ca = mfmaH(ih[kt], bl, ca);
            cb = mfmaH(il[kt], bh, cb);
        }
        float xv[4]; half4 hv;
        #pragma unroll
        for (int r = 0; r < 4; ++r){
            float v = m[r] + (ca[r] + cb[r])*INV2048;
            y[r] = v; yh[r] = v; xv[r] = v; bmv[r] = 0.f;
            hv[r] = (_Float16)v;
        }
        storeA1(xv, A1h, A1l, b, w8*16 + 4*q);
        stChunk(Y1, 256, b, w8*16 + 4*q, hv);
    }

    const float ts0  = ts[0];
    const float dtv  = ts[1] - ts0;
    const float sqdt = sqrtf(dtv);

    #pragma unroll 1
    for (int t = 0; t < T; ++t){
        const float tval = ts0 + (float)t * dtv;
        const int par = t & 1;
        float dWv[4] = {0.f,0.f,0.f,0.f};
        // P0: predictor -> A1
        if (t > 0){
            float nv[4];
            #pragma unroll
            for (int r = 0; r < 4; ++r){
                dWv[r] = bmv[r] * sqdt;
                float nyh = 2.0f*y[r] - yh[r] + fp[r]*dtv + gp[r]*dWv[r];
                yh[r] = nyh; nv[r] = nyh;
            }
            storeA1(nv, A1h, A1l, b, w8*16 + 4*q);
        }
        if (tid < 256) s_bp[tid] = s_b1[tid] + tval * s_w1r0[tid];
        __syncthreads();                                                  // B0
        // bm prefetch for next step
        if (t < T-1){
            f32x4 bv = *reinterpret_cast<const f32x4*>(
                bm + (size_t)t*(NB*H) + (size_t)(row0+b)*H + w8*16 + 4*q);
            #pragma unroll
            for (int r = 0; r < 4; ++r) bmv[r] = bv[r];
        }
        // P1: L1 (K=128)
        layerPairReg<4, true>(W1h[0], W1h[1], W1l[0], W1l[1],
                              A1h, A1l, 256, H1h, H1l, s_bp, 2*w8, 2*w8+1, b, q);
        __syncthreads();                                                  // B1
        // P2: L2 (K=256)
        layerPairLds<8, true>(W2h[0], W2h[1], Wlo2, (2*w8)*8, (2*w8+1)*8, l,
                              H1h, H1l, 512, H2h, H2l, s_b2, 2*w8, 2*w8+1, b, q);
        __syncthreads();                                                  // B2
        // P3: L3 -> own v3; publish early (system-scope write-through stores)
        f32x4 v3 = layerOneLds8(W3h, Wlo3, w8*8, l, H2h, H2l, s_b3, w8, b, q);
        st_sys4(Xown + par*2304 + (b*128 + w8*16 + 4*q), v3);
        // P5': fused lagged readout (tr = t-1): hides store-ack before Bv
        f32x4 pr = {0.f,0.f,0.f,0.f};
        if (t > 0){
            f32x4 m = *reinterpret_cast<const f32x4*>(s_rb1h + w8*16 + 4*q);
            #pragma unroll
            for (int kt = 0; kt < 4; ++kt) m = mfmaH(WR1[kt], ldB(Y1, 256, kt, b, q), m);
            half4 hv;
            #pragma unroll
            for (int r = 0; r < 4; ++r) hv[r] = (_Float16)ftanh(m[r]);
            *reinterpret_cast<half4*>(&Rb[w8*256 + b*16 + 4*q]) = hv;     // same-wave LDS, in-order
            half8 bf = *reinterpret_cast<const half8*>(&Rb[w8*256 + b*16 + (q&1)*8]);
            pr = mfmaH(WR2, bf, pr);   // A-frag zero-padded: q>=2 garbage B killed by zeros
        }
        __syncthreads();                                                  // Bv (drains v3 sys-store acks)
        if (tid == 0) flag_release_sys(flagOwn, t + 1);
        // atomics issued after release: their acks drain during the poll window
        if (t > 0 && q < 2){
            float* op = out + (size_t)(row0+b)*(T*D) + (size_t)(t-1)*D + 4*q;
            #pragma unroll
            for (int r = 0; r < 4; ++r) atomicAdd(op + r, pr[r]);
        }
        if (tid == 0) flag_poll_sys(flagPar, t + 1);
        __syncthreads();                                                  // B7
        // read partner v3 (system-scope: fresh at IF$)
        f32x4 vp = ld_sys4(Xpar + par*2304 + (b*128 + w8*16 + 4*q));
        // P4: corrector + Y1
        {
            half4 hv;
            #pragma unroll
            for (int r = 0; r < 4; ++r){
                float fn = role ? vp[r] : v3[r];
                float gn = role ? v3[r] : vp[r];
                if (t > 0) y[r] += 0.5f*dtv*(fp[r] + fn) + 0.5f*(gp[r] + gn)*dWv[r];
                fp[r] = fn; gp[r] = gn;
                hv[r] = (_Float16)y[r];
            }
            stChunk(Y1, 256, b, w8*16 + 4*q, hv);
        }
    }

    // ---- flush: fused readout for tr = T-1 ----
    __syncthreads();
    {
        f32x4 m = *reinterpret_cast<const f32x4*>(s_rb1h + w8*16 + 4*q);
        #pragma unroll
        for (int kt = 0; kt < 4; ++kt) m = mfmaH(WR1[kt], ldB(Y1, 256, kt, b, q), m);
        half4 hv;
        #pragma unroll
        for (int r = 0; r < 4; ++r) hv[r] = (_Float16)ftanh(m[r]);
        *reinterpret_cast<half4*>(&Rb[w8*256 + b*16 + 4*q]) = hv;
        half8 bf = *reinterpret_cast<const half8*>(&Rb[w8*256 + b*16 + (q&1)*8]);
        f32x4 pr = {0.f,0.f,0.f,0.f};
        pr = mfmaH(WR2, bf, pr);
        if (q < 2){
            float* op = out + (size_t)(row0+b)*(T*D) + (size_t)(T-1)*D + 4*q;
            #pragma unroll
            for (int r = 0; r < 4; ++r) atomicAdd(op + r, pr[r]);
        }
    }
}

extern "C" void kernel_launch(void* const* d_in, const int* in_sizes, int n_in,
                              void* d_out, int out_size, void* d_ws, size_t ws_size,
                              hipStream_t stream)
{
    const float* init_noise = (const float*)d_in[0];
    const float* ts  = (const float*)d_in[1];
    const float* bm  = (const float*)d_in[2];
    const float* iW1 = (const float*)d_in[3];
    const float* ib1 = (const float*)d_in[4];
    const float* iW2 = (const float*)d_in[5];
    const float* ib2 = (const float*)d_in[6];
    const float* fW1 = (const float*)d_in[7];
    const float* fb1 = (const float*)d_in[8];
    const float* fW2 = (const float*)d_in[9];
    const float* fb2 = (const float*)d_in[10];
    const float* fW3 = (const float*)d_in[11];
    const float* fb3 = (const float*)d_in[12];
    const float* gW1 = (const float*)d_in[13];
    const float* gb1 = (const float*)d_in[14];
    const float* gW2 = (const float*)d_in[15];
    const float* gb2 = (const float*)d_in[16];
    const float* gW3 = (const float*)d_in[17];
    const float* gb3 = (const float*)d_in[18];
    const float* rW1 = (const float*)d_in[19];
    const float* rb1 = (const float*)d_in[20];
    const float* rW2 = (const float*)d_in[21];
    const float* rb2 = (const float*)d_in[22];

    unsigned char* ws = (unsigned char*)d_ws;

    zero_flags<<<dim3(1), dim3(256), 0, stream>>>(ws);
    pack_weights<<<dim3(NFRAG), dim3(64), 0, stream>>>(
        fW1, fW2, fW3, gW1, gW2, gW3, rW1, rW2, iW2, ws);
    prefill_out<<<dim3(1024), dim3(256), 0, stream>>>(rb2, (float*)d_out);
    sde_main<<<dim3(128), dim3(512), 0, stream>>>(
        init_noise, ts, bm, iW1, ib1, ib2,
        fb1, fW1, fb2, fb3,
        gb1, gW1, gb2, gb3,
        rb1, ws, (float*)d_out);
}

// Round 8
// 2037.316 us; speedup vs baseline: 1.3846x; 1.1454x over previous
//
#include <hip/hip_runtime.h>
#include <hip/hip_bf16.h>
#include <math.h>

#define NB  1024
#define T   256
#define H   128
#define Z0  64
#define D   8
#define MH  256

typedef __attribute__((ext_vector_type(8))) _Float16 half8;
typedef __attribute__((ext_vector_type(4))) _Float16 half4;
typedef __attribute__((ext_vector_type(4))) float f32x4;
typedef unsigned long long u64;

#define INV2048 4.8828125e-4f

// fragment indices (hi16/lo16 frag = 1024B, lo8 frag = 512B)
#define OFF_F1 0
#define OFF_F2 64
#define OFF_F3 192
#define OFF_G1 256
#define OFF_G2 320
#define OFF_G3 448
#define OFF_R1 512
#define OFF_R2 576
#define OFF_I2 584
#define NFRAG  648

// d_ws layout (bytes)
#define WS_HI16 0
#define WS_LO16 663552                     // 648*1024
#define WS_LO8  1327104                    // + 648*1024
#define WS_EX   1658880                    // 64 groups * 36864 (2 roles * 2 parity * 9216)
#define WS_FLG  4018176                    // 64 groups * 256B int flags

// pin a value in VGPRs: compiler can no longer rematerialize it from memory
#define KEEP(x) asm volatile("" : "+v"(x))

__device__ __forceinline__ f32x4 mfmaH(half8 a, half8 b, f32x4 c){
    return __builtin_amdgcn_mfma_f32_16x16x32_f16(a, b, c, 0, 0, 0);
}
__device__ __forceinline__ float ftanh(float x){
    float e = __expf(2.0f * x);
    return 1.0f - 2.0f * __builtin_amdgcn_rcpf(e + 1.0f);
}
// e5m2 byte = round-half-up of fp16's upper byte
__device__ __forceinline__ unsigned char f16_to_e5m2(_Float16 h){
    unsigned short hu = *reinterpret_cast<unsigned short*>(&h);
    return (unsigned char)((hu + 0x80) >> 8);
}
// exact e5m2 -> fp16 expansion of 8 packed bytes (b<<8 per element)
__device__ __forceinline__ half8 expandQ(u64 qw){
    unsigned int lo = (unsigned int)qw, hi = (unsigned int)(qw >> 32);
    union { unsigned int u[4]; half8 h; } u;
    u.u[0] = ((lo & 0xFFu) << 8) | ((lo & 0xFF00u) << 16);
    u.u[1] = ((lo >> 8) & 0xFF00u) | (lo & 0xFF000000u);
    u.u[2] = ((hi & 0xFFu) << 8) | ((hi & 0xFF00u) << 16);
    u.u[3] = ((hi >> 8) & 0xFF00u) | (hi & 0xFF000000u);
    return u.h;
}

// ---- system-scope fine-grained exchange (write-through to IF$, no L2 wb/inv) ----
__device__ __forceinline__ void st_sys4(float* p, f32x4 v){
    union { f32x4 v; u64 q[2]; } c; c.v = v;
    u64* d = reinterpret_cast<u64*>(p);
    __hip_atomic_store(d,     c.q[0], __ATOMIC_RELAXED, __HIP_MEMORY_SCOPE_SYSTEM);
    __hip_atomic_store(d + 1, c.q[1], __ATOMIC_RELAXED, __HIP_MEMORY_SCOPE_SYSTEM);
}
__device__ __forceinline__ f32x4 ld_sys4(float* p){
    union { u64 q[2]; f32x4 v; } c;
    u64* s = reinterpret_cast<u64*>(p);
    c.q[0] = __hip_atomic_load(s,     __ATOMIC_RELAXED, __HIP_MEMORY_SCOPE_SYSTEM);
    c.q[1] = __hip_atomic_load(s + 1, __ATOMIC_RELAXED, __HIP_MEMORY_SCOPE_SYSTEM);
    return c.v;
}
__device__ __forceinline__ void st_sys1(float* p, float v){
    union { float f; int i; } c; c.f = v;
    __hip_atomic_store(reinterpret_cast<int*>(p), c.i, __ATOMIC_RELAXED, __HIP_MEMORY_SCOPE_SYSTEM);
}
__device__ __forceinline__ float ld_sys1(float* p){
    union { int i; float f; } c;
    c.i = __hip_atomic_load(reinterpret_cast<int*>(p), __ATOMIC_RELAXED, __HIP_MEMORY_SCOPE_SYSTEM);
    return c.f;
}
__device__ __forceinline__ void flag_release_sys(int* p, int v){
    // callers guarantee a preceding __syncthreads (drains vmcnt; sc1 data stores
    // retire only once acked at the coherence point), so a relaxed store suffices.
    __hip_atomic_store(p, v, __ATOMIC_RELAXED, __HIP_MEMORY_SCOPE_SYSTEM);
}
__device__ __forceinline__ void flag_poll_sys(int* p, int v){
    while (__hip_atomic_load(p, __ATOMIC_RELAXED, __HIP_MEMORY_SCOPE_SYSTEM) < v)
        __builtin_amdgcn_s_sleep(2);
}

// ---- swizzled LDS accessors: [b][k] fp16 rows ----
// swizzle v2 (R7-validated: conflicts 6.09e7 -> 1.47e7): sb=512 rows ->
// XOR (b&15)<<4 ^ (b&1)<<8; sb=256 rows -> (b&15)<<4. Bijective within a row;
// write & read use the same XOR.
__device__ __forceinline__ int swz(int sb, int b){
    return ((b & 15) << 4) ^ ((sb == 512) ? ((b & 1) << 8) : 0);
}
__device__ __forceinline__ half8 ldB(const _Float16* buf, int sb, int kt, int b, int q){
    const char* p = reinterpret_cast<const char*>(buf);
    return *reinterpret_cast<const half8*>(p + ((b*sb + kt*64 + q*16) ^ swz(sb, b)));
}
__device__ __forceinline__ void stChunk(_Float16* buf, int sb, int b, int k0, half4 v){
    char* p = reinterpret_cast<char*>(buf);
    *reinterpret_cast<half4*>(p + ((b*sb + k0*2) ^ swz(sb, b))) = v;
}
__device__ __forceinline__ void stOne(_Float16* buf, int sb, int b, int k, _Float16 v){
    char* p = reinterpret_cast<char*>(buf);
    *reinterpret_cast<_Float16*>(p + ((b*sb + k*2) ^ swz(sb, b))) = v;
}
__device__ __forceinline__ u64 ldsQ(const char* base, int fragRel, int l){
    return *reinterpret_cast<const u64*>(base + fragRel*512 + l*8);
}

template<bool DOTANH>
__device__ __forceinline__ void storeOut(f32x4 m, f32x4 c, _Float16* Oh, _Float16* Ol, int b, int k0){
    half4 hh, ll;
    #pragma unroll
    for (int r = 0; r < 4; ++r){
        float v = m[r] + c[r]*INV2048;
        if (DOTANH) v = ftanh(v);
        _Float16 h = (_Float16)v;
        hh[r] = h;
        ll[r] = (_Float16)((v - (float)h)*2048.0f);
    }
    stChunk(Oh, 512, b, k0, hh);
    stChunk(Ol, 512, b, k0, ll);
}
__device__ __forceinline__ void storeA1(const float* v4, _Float16* Oh, _Float16* Ol, int b, int k0){
    half4 hh, ll;
    #pragma unroll
    for (int r = 0; r < 4; ++r){
        float v = v4[r];
        _Float16 h = (_Float16)v;
        hh[r] = h;
        ll[r] = (_Float16)((v - (float)h)*2048.0f);
    }
    stChunk(Oh, 256, b, k0, hh);
    stChunk(Ol, 256, b, k0, ll);
}
__device__ __forceinline__ void stOne2(_Float16* Oh, _Float16* Ol, int b, int k, float v){
    _Float16 h = (_Float16)v;
    stOne(Oh, 512, b, k, h);
    stOne(Ol, 512, b, k, (_Float16)((v - (float)h)*2048.0f));
}

// L1: weights hi+lo fully in VGPRs
template<int KT, bool DOTANH>
__device__ __forceinline__ void layerPairReg(
    const half8* Wh0, const half8* Wh1, const half8* Wl0, const half8* Wl1,
    const _Float16* Bh, const _Float16* Bl, int sbIn,
    _Float16* Oh, _Float16* Ol, const float* bias, int n0, int n1, int b, int q)
{
    f32x4 m0 = *reinterpret_cast<const f32x4*>(bias + n0*16 + 4*q);
    f32x4 m1 = *reinterpret_cast<const f32x4*>(bias + n1*16 + 4*q);
    f32x4 c0 = {0.f,0.f,0.f,0.f}, c1 = {0.f,0.f,0.f,0.f};
    #pragma unroll
    for (int kt = 0; kt < KT; ++kt){
        half8 bh = ldB(Bh, sbIn, kt, b, q);
        half8 bl = ldB(Bl, sbIn, kt, b, q);
        m0 = mfmaH(Wh0[kt], bh, m0);
        m1 = mfmaH(Wh1[kt], bh, m1);
        c0 = mfmaH(Wh0[kt], bl, c0);
        c1 = mfmaH(Wh1[kt], bl, c1);
        c0 = mfmaH(Wl0[kt], bh, c0);
        c1 = mfmaH(Wl1[kt], bh, c1);
    }
    storeOut<DOTANH>(m0, c0, Oh, Ol, b, n0*16 + 4*q);
    storeOut<DOTANH>(m1, c1, Oh, Ol, b, n1*16 + 4*q);
}
// L2: hi in VGPRs, lo as e5m2 bytes in LDS expanded to fp16
template<int KT, bool DOTANH>
__device__ __forceinline__ void layerPairLds(
    const half8* Wh0, const half8* Wh1, const char* WloLds, int f0, int f1, int l,
    const _Float16* Bh, const _Float16* Bl, int sbIn,
    _Float16* Oh, _Float16* Ol, const float* bias, int n0, int n1, int b, int q)
{
    f32x4 m0 = *reinterpret_cast<const f32x4*>(bias + n0*16 + 4*q);
    f32x4 m1 = *reinterpret_cast<const f32x4*>(bias + n1*16 + 4*q);
    f32x4 c0 = {0.f,0.f,0.f,0.f}, c1 = {0.f,0.f,0.f,0.f};
    #pragma unroll
    for (int kt = 0; kt < KT; ++kt){
        half8 bh = ldB(Bh, sbIn, kt, b, q);
        half8 bl = ldB(Bl, sbIn, kt, b, q);
        half8 w0l = expandQ(ldsQ(WloLds, f0 + kt, l));
        half8 w1l = expandQ(ldsQ(WloLds, f1 + kt, l));
        m0 = mfmaH(Wh0[kt], bh, m0);
        m1 = mfmaH(Wh1[kt], bh, m1);
        c0 = mfmaH(Wh0[kt], bl, c0);
        c1 = mfmaH(Wh1[kt], bl, c1);
        c0 = mfmaH(w0l, bh, c0);
        c1 = mfmaH(w1l, bh, c1);
    }
    storeOut<DOTANH>(m0, c0, Oh, Ol, b, n0*16 + 4*q);
    storeOut<DOTANH>(m1, c1, Oh, Ol, b, n1*16 + 4*q);
}
// L3: hi VGPR + e5m2-LDS lo, result fp32 regs
__device__ __forceinline__ f32x4 layerOneLds8(
    const half8* Wh, const char* WloLds, int f0, int l,
    const _Float16* Bh, const _Float16* Bl,
    const float* bias, int n0, int b, int q)
{
    f32x4 m = *reinterpret_cast<const f32x4*>(bias + n0*16 + 4*q);
    f32x4 c = {0.f,0.f,0.f,0.f};
    #pragma unroll
    for (int kt = 0; kt < 8; ++kt){
        half8 bh = ldB(Bh, 512, kt, b, q);
        half8 bl = ldB(Bl, 512, kt, b, q);
        half8 wl = expandQ(ldsQ(WloLds, f0 + kt, l));
        m = mfmaH(Wh[kt], bh, m);
        c = mfmaH(Wh[kt], bl, c);
        c = mfmaH(wl, bh, c);
    }
    #pragma unroll
    for (int r = 0; r < 4; ++r) m[r] += c[r]*INV2048;
    return m;
}

// ---- pack: hi16 + lo16 (fp16) + lo8 (e5m2 of scaled residual) ----
__global__ __launch_bounds__(64)
void pack_weights(const float* __restrict__ fW1, const float* __restrict__ fW2, const float* __restrict__ fW3,
                  const float* __restrict__ gW1, const float* __restrict__ gW2, const float* __restrict__ gW3,
                  const float* __restrict__ rW1, const float* __restrict__ rW2, const float* __restrict__ iW2,
                  unsigned char* __restrict__ ws)
{
    int f = blockIdx.x, l = threadIdx.x;
    const float* W; int KT, base, ld, ncols;
    if      (f <  64) { W = fW1+256; KT=4; base=OFF_F1; ld=256; ncols=256; }  // skip t-row 0
    else if (f < 192) { W = fW2;     KT=8; base=OFF_F2; ld=256; ncols=256; }
    else if (f < 256) { W = fW3;     KT=8; base=OFF_F3; ld=128; ncols=128; }
    else if (f < 320) { W = gW1+256; KT=4; base=OFF_G1; ld=256; ncols=256; }
    else if (f < 448) { W = gW2;     KT=8; base=OFF_G2; ld=256; ncols=256; }
    else if (f < 512) { W = gW3;     KT=8; base=OFF_G3; ld=128; ncols=128; }
    else if (f < 576) { W = rW1;     KT=4; base=OFF_R1; ld=256; ncols=256; }
    else if (f < 584) { W = rW2;     KT=8; base=OFF_R2; ld=8;   ncols=8;   }
    else              { W = iW2;     KT=8; base=OFF_I2; ld=128; ncols=128; }
    int rel = f - base, n = rel / KT, kt = rel % KT;
    int krow = kt*32 + (l >> 4)*8;
    int col  = n*16  + (l & 15);
    half8 vh, vl; u64 qw = 0;
    #pragma unroll
    for (int j = 0; j < 8; ++j){
        float x = (col < ncols) ? W[(size_t)(krow + j)*ld + col] : 0.0f;
        _Float16 h = (_Float16)x;
        vh[j] = h;
        _Float16 r16 = (_Float16)((x - (float)h) * 2048.0f);
        vl[j] = r16;
        qw |= (u64)f16_to_e5m2(r16) << (8*j);
    }
    reinterpret_cast<half8*>(ws + WS_HI16)[(size_t)f*64 + l] = vh;
    reinterpret_cast<half8*>(ws + WS_LO16)[(size_t)f*64 + l] = vl;
    *reinterpret_cast<u64*>(ws + WS_LO8 + (size_t)f*512 + l*8) = qw;
}

__global__ __launch_bounds__(256)
void zero_flags(unsigned char* ws){
    int* fl = (int*)(ws + WS_FLG);
    #pragma unroll
    for (int i = 0; i < 16; ++i) fl[threadIdx.x + i*256] = 0;
}

// ---- main: 128 WGs (64 groups x {f,g}), 512 thr, weights resident ----
__global__ __launch_bounds__(512, 2)
void sde_main(const float* __restrict__ init_noise, const float* __restrict__ ts,
              const float* __restrict__ bm,
              const float* __restrict__ iW1, const float* __restrict__ ib1,
              const float* __restrict__ ib2,
              const float* __restrict__ fb1, const float* __restrict__ fW1r,
              const float* __restrict__ fb2, const float* __restrict__ fb3,
              const float* __restrict__ gb1, const float* __restrict__ gW1r,
              const float* __restrict__ gb2, const float* __restrict__ gb3,
              const float* __restrict__ rb1, const float* __restrict__ rb2,
              unsigned char* __restrict__ ws,
              float* __restrict__ out)
{
    const int tid  = threadIdx.x;
    const int wv   = tid >> 6;         // 0..7
    const int l    = tid & 63;
    const int q    = l >> 4;
    const int b    = l & 15;
    const int bid  = blockIdx.x;
    const int role  = (bid >= 64) ? 1 : 0;        // 0=f, 1=g
    const int group = bid & 63;
    const int row0  = group * 16;
    const int w8    = wv;

    __shared__ __align__(16) char Wlo2[65536];            // own L2 lo8 frags
    __shared__ __align__(16) char Wlo3[32768];            // own L3 lo8 frags
    __shared__ __align__(16) _Float16 A1h[16*128], A1l[16*128];
    __shared__ __align__(16) _Float16 H1h[16*256], H1l[16*256];
    __shared__ __align__(16) _Float16 H2h[16*256], H2l[16*256];
    __shared__ __align__(16) _Float16 Y1[16*128];
    __shared__ __align__(16) float part[512];
    __shared__ __align__(16) float s_b1[256];
    __shared__ __align__(16) float s_w1r0[256];
    __shared__ __align__(16) float s_bp[256];
    __shared__ __align__(16) float s_b2[256];
    __shared__ __align__(16) float s_b3[128];
    __shared__ __align__(16) float s_rb1h[128];
    __shared__ __align__(16) float s_rb2[8];

    const float* b1p = role ? gb1 : fb1;
    const float* w1p = role ? gW1r : fW1r;
    const float* b2p = role ? gb2 : fb2;
    const float* b3p = role ? gb3 : fb3;
    const int o1 = role ? OFF_G1 : OFF_F1;
    const int o2 = role ? OFF_G2 : OFF_F2;
    const int o3 = role ? OFF_G3 : OFF_F3;

    // exchange blob: per group 36864B; per role 18432B; per parity 9216B
    // blob layout (floats): v3[2048] @0, partial[128] @2048
    char* exg = (char*)ws + WS_EX + (size_t)group*36864;
    float* Xown = (float*)(exg + role*18432);
    float* Xpar = (float*)(exg + (1-role)*18432);
    int* flags   = (int*)(ws + WS_FLG + (size_t)group*256);
    int* flagOwn = flags + role;
    int* flagPar = flags + (1 - role);

    // ---- staging ----
    if (tid < 256){ s_b1[tid] = b1p[tid]; s_w1r0[tid] = w1p[tid]; s_b2[tid] = b2p[tid]; }
    else if (tid < 384){ s_b3[tid-256] = b3p[tid-256]; }
    else { s_rb1h[tid-384] = rb1[role*128 + (tid-384)]; }
    if (tid < 8) s_rb2[tid] = rb2[tid];
    float* zb = reinterpret_cast<float*>(H2h);            // alias (init only)
    zb[tid]       = init_noise[row0*Z0 + tid];
    zb[tid + 512] = init_noise[row0*Z0 + 512 + tid];
    {   // stage own lo8 tables into LDS
        f32x4* d2 = (f32x4*)Wlo2; const f32x4* s2 = (const f32x4*)(ws + WS_LO8 + (size_t)o2*512);
        #pragma unroll
        for (int i = 0; i < 8; ++i) d2[tid + i*512] = s2[tid + i*512];
        f32x4* d3 = (f32x4*)Wlo3; const f32x4* s3 = (const f32x4*)(ws + WS_LO8 + (size_t)o3*512);
        #pragma unroll
        for (int i = 0; i < 4; ++i) d3[tid + i*512] = s3[tid + i*512];
    }
    // ---- resident weights -> VGPRs ----
    const half8* hi  = reinterpret_cast<const half8*>(ws + WS_HI16);
    const half8* lo16 = reinterpret_cast<const half8*>(ws + WS_LO16);
    half8 W1h[2][4], W1l[2][4], W2h[2][8], W3h[8], WR1[4], WR2;
    #pragma unroll
    for (int kt = 0; kt < 4; ++kt){
        W1h[0][kt] = hi  [(size_t)(o1 + (2*w8  )*4 + kt)*64 + l];
        W1h[1][kt] = hi  [(size_t)(o1 + (2*w8+1)*4 + kt)*64 + l];
        W1l[0][kt] = lo16[(size_t)(o1 + (2*w8  )*4 + kt)*64 + l];
        W1l[1][kt] = lo16[(size_t)(o1 + (2*w8+1)*4 + kt)*64 + l];
        WR1[kt]    = hi  [(size_t)(OFF_R1 + (role*8 + w8)*4 + kt)*64 + l];
    }
    #pragma unroll
    for (int kt = 0; kt < 8; ++kt){
        W2h[0][kt] = hi[(size_t)(o2 + (2*w8  )*8 + kt)*64 + l];
        W2h[1][kt] = hi[(size_t)(o2 + (2*w8+1)*8 + kt)*64 + l];
        W3h[kt]    = hi[(size_t)(o3 + w8*8 + kt)*64 + l];
    }
    WR2 = hi[(size_t)(OFF_R2 + role*4 + (w8 & 3))*64 + l];

    // pin the per-step weights in VGPRs (defeats rematerialization from memory)
    #pragma unroll
    for (int s = 0; s < 2; ++s){
        #pragma unroll
        for (int kt = 0; kt < 4; ++kt){ KEEP(W1h[s][kt]); KEEP(W1l[s][kt]); }
        #pragma unroll
        for (int kt = 0; kt < 8; ++kt){ KEEP(W2h[s][kt]); }
    }
    #pragma unroll
    for (int kt = 0; kt < 8; ++kt){ KEEP(W3h[kt]); }
    __syncthreads();

    // ---- init MLP layer 1 (fp32 VALU): h = tanh(z@iW1+ib1) -> H1 ----
    {
        const int c = tid & 255, hf = tid >> 8;
        float ac[8]; float bv = ib1[c];
        #pragma unroll
        for (int rr = 0; rr < 8; ++rr) ac[rr] = bv;
        for (int k = 0; k < Z0; ++k){
            float wt = iW1[k*256 + c];
            #pragma unroll
            for (int rr = 0; rr < 8; ++rr) ac[rr] += zb[(hf*8+rr)*Z0 + k] * wt;
        }
        #pragma unroll
        for (int rr = 0; rr < 8; ++rr) stOne2(H1h, H1l, hf*8+rr, c, ftanh(ac[rr]));
    }
    __syncthreads();

    // ---- init MLP layer 2 (MFMA, hi/lo fp16 transient): x0 -> state + A1 + Y1 ----
    float y[4], yh[4], fp[4], gp[4], bmv[4];
    {
        half8 ih[8], il[8];
        #pragma unroll
        for (int kt = 0; kt < 8; ++kt){
            ih[kt] = hi  [(size_t)(OFF_I2 + w8*8 + kt)*64 + l];
            il[kt] = lo16[(size_t)(OFF_I2 + w8*8 + kt)*64 + l];
        }
        f32x4 m = *reinterpret_cast<const f32x4*>(ib2 + w8*16 + 4*q);
        f32x4 c = {0.f,0.f,0.f,0.f};
        #pragma unroll
        for (int kt = 0; kt < 8; ++kt){
            half8 bh = ldB(H1h, 512, kt, b, q);
            half8 bl = ldB(H1l, 512, kt, b, q);
            m = mfmaH(ih[kt], bh, m);
            c = mfmaH(ih[kt], bl, c);
            c = mfmaH(il[kt], bh, c);
        }
        float xv[4]; half4 hv;
        #pragma unroll
        for (int r = 0; r < 4; ++r){
            float v = m[r] + c[r]*INV2048;
            y[r] = v; yh[r] = v; xv[r] = v; bmv[r] = 0.f;
            hv[r] = (_Float16)v;
        }
        storeA1(xv, A1h, A1l, b, w8*16 + 4*q);
        stChunk(Y1, 256, b, w8*16 + 4*q, hv);
    }

    const float ts0  = ts[0];
    const float dtv  = ts[1] - ts0;
    const float sqdt = sqrtf(dtv);

    #pragma unroll 1
    for (int t = 0; t < T; ++t){
        const float tval = ts0 + (float)t * dtv;
        const int par = t & 1;
        float dWv[4] = {0.f,0.f,0.f,0.f};
        // P0: predictor -> A1
        if (t > 0){
            float nv[4];
            #pragma unroll
            for (int r = 0; r < 4; ++r){
                dWv[r] = bmv[r] * sqdt;
                float nyh = 2.0f*y[r] - yh[r] + fp[r]*dtv + gp[r]*dWv[r];
                yh[r] = nyh; nv[r] = nyh;
            }
            storeA1(nv, A1h, A1l, b, w8*16 + 4*q);
        }
        if (tid < 256) s_bp[tid] = s_b1[tid] + tval * s_w1r0[tid];
        __syncthreads();                                                  // B0
        // bm prefetch for next step
        if (t < T-1){
            f32x4 bv = *reinterpret_cast<const f32x4*>(
                bm + (size_t)t*(NB*H) + (size_t)(row0+b)*H + w8*16 + 4*q);
            #pragma unroll
            for (int r = 0; r < 4; ++r) bmv[r] = bv[r];
        }
        // P1: L1 (K=128)
        layerPairReg<4, true>(W1h[0], W1h[1], W1l[0], W1l[1],
                              A1h, A1l, 256, H1h, H1l, s_bp, 2*w8, 2*w8+1, b, q);
        __syncthreads();                                                  // B1
        // P2: L2 (K=256)
        layerPairLds<8, true>(W2h[0], W2h[1], Wlo2, (2*w8)*8, (2*w8+1)*8, l,
                              H1h, H1l, 512, H2h, H2l, s_b2, 2*w8, 2*w8+1, b, q);
        __syncthreads();                                                  // B2
        // P3: L3 -> own v3; publish early (system-scope write-through stores)
        f32x4 v3 = layerOneLds8(W3h, Wlo3, w8*8, l, H2h, H2l, s_b3, w8, b, q);
        st_sys4(Xown + par*2304 + (b*128 + w8*16 + 4*q), v3);
        // P5: lagged readout L1 (tr = t-1) on Y1, hi-only; H1h free after B2
        {
            f32x4 m = *reinterpret_cast<const f32x4*>(s_rb1h + w8*16 + 4*q);
            #pragma unroll
            for (int kt = 0; kt < 4; ++kt) m = mfmaH(WR1[kt], ldB(Y1, 256, kt, b, q), m);
            half4 hv;
            #pragma unroll
            for (int r = 0; r < 4; ++r) hv[r] = (_Float16)ftanh(m[r]);
            stChunk(H1h, 512, b, w8*16 + 4*q, hv);
        }
        __syncthreads();                                                  // B56
        // P6: readout L2 partials (own K-half)
        {
            f32x4 pr = {0.f,0.f,0.f,0.f};
            pr = mfmaH(WR2, ldB(H1h, 512, (w8 & 3), b, q), pr);
            if (w8 < 4 && q < 2)
                *reinterpret_cast<f32x4*>(&part[((w8 & 3)*16 + b)*8 + 4*q]) = pr;
        }
        __syncthreads();                                                  // B6a
        // sum own partial + publish it (system-scope store)
        float s_own = 0.f;
        if (tid < 128){
            #pragma unroll
            for (int p = 0; p < 4; ++p) s_own += part[p*128 + tid];
            st_sys1(Xown + par*2304 + 2048 + tid, s_own);
        }
        __syncthreads();                                                  // Bpub (drains vmcnt)
        if (tid == 0) flag_release_sys(flagOwn, t + 1);
        if (tid == 0) flag_poll_sys(flagPar, t + 1);
        __syncthreads();                                                  // B7
        // read partner blob (system-scope loads: always fresh at IF$)
        f32x4 vp = ld_sys4(Xpar + par*2304 + (b*128 + w8*16 + 4*q));
        // out write for tr = t-1, own half of rows
        {
            const int tr = t - 1;
            const bool writer = role ? (tid >= 64 && tid < 128) : (tid < 64);
            if (tr >= 0 && writer){
                float vo = s_own + ld_sys1(Xpar + par*2304 + 2048 + tid) + s_rb2[tid & 7];
                out[(size_t)(row0 + (tid >> 3))*(T*D) + (size_t)tr*D + (tid & 7)] = vo;
            }
        }
        // P4: corrector + Y1
        {
            half4 hv;
            #pragma unroll
            for (int r = 0; r < 4; ++r){
                float fn = role ? vp[r] : v3[r];
                float gn = role ? v3[r] : vp[r];
                if (t > 0) y[r] += 0.5f*dtv*(fp[r] + fn) + 0.5f*(gp[r] + gn)*dWv[r];
                fp[r] = fn; gp[r] = gn;
                hv[r] = (_Float16)y[r];
            }
            stChunk(Y1, 256, b, w8*16 + 4*q, hv);
        }
    }

    // ---- flush: readout for tr = T-1 ----
    __syncthreads();
    {
        f32x4 m = *reinterpret_cast<const f32x4*>(s_rb1h + w8*16 + 4*q);
        #pragma unroll
        for (int kt = 0; kt < 4; ++kt) m = mfmaH(WR1[kt], ldB(Y1, 256, kt, b, q), m);
        half4 hv;
        #pragma unroll
        for (int r = 0; r < 4; ++r) hv[r] = (_Float16)ftanh(m[r]);
        stChunk(H1h, 512, b, w8*16 + 4*q, hv);
    }
    __syncthreads();
    {
        f32x4 pr = {0.f,0.f,0.f,0.f};
        pr = mfmaH(WR2, ldB(H1h, 512, (w8 & 3), b, q), pr);
        if (w8 < 4 && q < 2)
            *reinterpret_cast<f32x4*>(&part[((w8 & 3)*16 + b)*8 + 4*q]) = pr;
    }
    __syncthreads();
    {
        const int par = T & 1;           // 0
        float s_own = 0.f;
        if (tid < 128){
            #pragma unroll
            for (int p = 0; p < 4; ++p) s_own += part[p*128 + tid];
            st_sys1(Xown + par*2304 + 2048 + tid, s_own);
        }
        __syncthreads();
        if (tid == 0) flag_release_sys(flagOwn, T + 1);
        if (tid == 0) flag_poll_sys(flagPar, T + 1);
        __syncthreads();
        const bool writer = role ? (tid >= 64 && tid < 128) : (tid < 64);
        if (writer){
            float vo = s_own + ld_sys1(Xpar + par*2304 + 2048 + tid) + s_rb2[tid & 7];
            out[(size_t)(row0 + (tid >> 3))*(T*D) + (size_t)(T-1)*D + (tid & 7)] = vo;
        }
    }
}

extern "C" void kernel_launch(void* const* d_in, const int* in_sizes, int n_in,
                              void* d_out, int out_size, void* d_ws, size_t ws_size,
                              hipStream_t stream)
{
    const float* init_noise = (const float*)d_in[0];
    const float* ts  = (const float*)d_in[1];
    const float* bm  = (const float*)d_in[2];
    const float* iW1 = (const float*)d_in[3];
    const float* ib1 = (const float*)d_in[4];
    const float* iW2 = (const float*)d_in[5];
    const float* ib2 = (const float*)d_in[6];
    const float* fW1 = (const float*)d_in[7];
    const float* fb1 = (const float*)d_in[8];
    const float* fW2 = (const float*)d_in[9];
    const float* fb2 = (const float*)d_in[10];
    const float* fW3 = (const float*)d_in[11];
    const float* fb3 = (const float*)d_in[12];
    const float* gW1 = (const float*)d_in[13];
    const float* gb1 = (const float*)d_in[14];
    const float* gW2 = (const float*)d_in[15];
    const float* gb2 = (const float*)d_in[16];
    const float* gW3 = (const float*)d_in[17];
    const float* gb3 = (const float*)d_in[18];
    const float* rW1 = (const float*)d_in[19];
    const float* rb1 = (const float*)d_in[20];
    const float* rW2 = (const float*)d_in[21];
    const float* rb2 = (const float*)d_in[22];

    unsigned char* ws = (unsigned char*)d_ws;

    zero_flags<<<dim3(1), dim3(256), 0, stream>>>(ws);
    pack_weights<<<dim3(NFRAG), dim3(64), 0, stream>>>(
        fW1, fW2, fW3, gW1, gW2, gW3, rW1, rW2, iW2, ws);
    sde_main<<<dim3(128), dim3(512), 0, stream>>>(
        init_noise, ts, bm, iW1, ib1, ib2,
        fb1, fW1, fb2, fb3,
        gb1, gW1, gb2, gb3,
        rb1, rb2, ws, (float*)d_out);
}